// Round 1
// baseline (487.864 us; speedup 1.0000x reference)
//
#include <hip/hip_runtime.h>
#include <math.h>

// Problem constants (fixed by the reference):
#define BB 32     // batch
#define NN 128    // nodes
#define CC 16     // in_ch
#define OO 32     // out_ch
#define II 32     // in_dim
#define JJ 32     // out_dim
#define MM (NN*CC)  // 2048 input capsules per (b, out_ch)
static constexpr float EPS_SQ = 1e-11f;

// Workspace layout (floats):
//   bij [BB][OO][CC][NN]   (routing logits, reordered m = (c,n); softmax is
//                           permutation-invariant over m so this is safe)
//   mx  [BB][OO]           (row max for softmax)
//   rinv[BB][OO]           (1/rowsum for softmax)
//   cx  [BB][CC][OO][II]   (softmax-weighted x: sum_n c * x)
//   v   [BB][OO][JJ]       (squashed output capsules)

// ---- softmax stats over the m=2048 axis, one block per (b,o) row ----
__global__ __launch_bounds__(256) void k_softmax_stats(
    const float* __restrict__ bij, float* __restrict__ mx, float* __restrict__ rinv) {
  int row = blockIdx.x;                       // b*OO + o
  const float* p = bij + (size_t)row * MM;
  int tid = threadIdx.x;
  float vals[8];
  float m = -INFINITY;
  #pragma unroll
  for (int k = 0; k < 8; ++k) { vals[k] = p[tid + k * 256]; m = fmaxf(m, vals[k]); }
  #pragma unroll
  for (int off = 32; off > 0; off >>= 1) m = fmaxf(m, __shfl_xor(m, off));
  __shared__ float smax[4];
  int wave = tid >> 6;
  if ((tid & 63) == 0) smax[wave] = m;
  __syncthreads();
  m = fmaxf(fmaxf(smax[0], smax[1]), fmaxf(smax[2], smax[3]));
  float s = 0.f;
  #pragma unroll
  for (int k = 0; k < 8; ++k) s += __expf(vals[k] - m);
  #pragma unroll
  for (int off = 32; off > 0; off >>= 1) s += __shfl_xor(s, off);
  __shared__ float ssum[4];
  if ((tid & 63) == 0) ssum[wave] = s;
  __syncthreads();
  if (tid == 0) {
    mx[row]   = m;
    rinv[row] = 1.0f / (ssum[0] + ssum[1] + ssum[2] + ssum[3]);
  }
}

// ---- cx[b,c,o,i] = sum_n softmax(bij)[b,o,(c,n)] * x[b,n,c,i];  block per (b,c) ----
__global__ __launch_bounds__(1024) void k_cx(
    const float* __restrict__ x, const float* __restrict__ bij,
    const float* __restrict__ mx, const float* __restrict__ rinv,
    float* __restrict__ cx) {
  int b = blockIdx.x / CC, c = blockIdx.x % CC;
  __shared__ float coef[OO][NN];       // 16 KB
  __shared__ float xs[NN][II + 1];     // ~16.5 KB, +1 pad (bank-conflict-free columns)
  int tid = threadIdx.x;
  #pragma unroll
  for (int k = 0; k < 4; ++k) {
    int idx = tid + k * 1024;          // = o*NN + n, coalesced in n
    int o = idx >> 7, n = idx & 127;
    int row = b * OO + o;
    coef[o][n] = __expf(bij[((size_t)row * CC + c) * NN + n] - mx[row]) * rinv[row];
  }
  #pragma unroll
  for (int k = 0; k < 4; ++k) {
    int idx = tid + k * 1024;          // = n*II + i, coalesced in i
    int n = idx >> 5, i = idx & 31;
    xs[n][i] = x[(((size_t)b * NN + n) * CC + c) * II + i];
  }
  __syncthreads();
  int o = tid >> 5, i = tid & 31;
  float acc = 0.f;
  #pragma unroll 8
  for (int n = 0; n < NN; ++n) acc += coef[o][n] * xs[n][i];  // coef broadcast, xs conflict-free
  cx[(((size_t)b * CC + c) * OO + o) * II + i] = acc;
}

// ---- s[b,o,j] = sum_{c,i} cx * W; squash -> v (and final outputs); block per b ----
__global__ __launch_bounds__(1024) void k_squash(
    const float* __restrict__ cx, const float* __restrict__ W,
    float* __restrict__ v, float* __restrict__ out, int write_out) {
  int b = blockIdx.x;
  int tid = threadIdx.x, o = tid >> 5, j = tid & 31;
  const float* cxb = cx + (size_t)b * CC * OO * II;
  float acc = 0.f;
  for (int c = 0; c < CC; ++c) {
    #pragma unroll
    for (int i = 0; i < II; ++i) {
      // cx read is broadcast across the 32 j-lanes; W read is j-coalesced
      acc += cxb[(c * OO + o) * II + i] * W[(((size_t)c * OO + o) * II + i) * JJ + j];
    }
  }
  // mag_sq = sum_j s^2 within each 32-lane j-group (o = tid>>5 aligns groups)
  float msq = acc * acc;
  #pragma unroll
  for (int off = 16; off > 0; off >>= 1) msq += __shfl_xor(msq, off);
  float mag = sqrtf(msq) + EPS_SQ;
  float a   = msq / (1.0f + msq);
  float vv  = a * acc / mag;
  v[(size_t)b * OO * JJ + tid] = vv;
  if (write_out) {
    out[(size_t)b * OO * JJ + tid] = vv;                 // v_j: [B,1,O,J] flat
    if (j == 0) out[BB * OO * JJ + b * OO + o] = a;      // a_j: [B,1,O,1] flat
  }
}

// ---- Wv[o,i] = sum_j W*v (LDS), then bij[b,o,(c,n)] += sum_i x[b,n,c,i]*Wv[o,i];
//      block per (b,c) ----
__global__ __launch_bounds__(1024) void k_update(
    const float* __restrict__ x, const float* __restrict__ W,
    const float* __restrict__ v, float* __restrict__ bij) {
  int b = blockIdx.x / CC, c = blockIdx.x % CC;
  int tid = threadIdx.x;
  __shared__ float vs[OO * JJ];        // 4 KB
  __shared__ float wv[OO][II];         // 4 KB
  __shared__ float xs[NN][II + 1];     // ~16.5 KB, pad kills the 32-way conflict below
  vs[tid] = v[(size_t)b * OO * JJ + tid];
  #pragma unroll
  for (int k = 0; k < 4; ++k) {
    int idx = tid + k * 1024;
    int n = idx >> 5, i = idx & 31;
    xs[n][i] = x[(((size_t)b * NN + n) * CC + c) * II + i];
  }
  __syncthreads();
  {
    int o = tid >> 5, i = tid & 31;
    float acc = 0.f;
    #pragma unroll
    for (int j = 0; j < JJ; ++j)
      acc += W[(((size_t)c * OO + o) * II + i) * JJ + j] * vs[o * JJ + j];
    wv[o][i] = acc;
  }
  __syncthreads();
  int n0 = tid & 31, o = tid >> 5;
  float* bp = bij + ((size_t)(b * OO + o) * CC + c) * NN;
  #pragma unroll
  for (int k = 0; k < 4; ++k) {
    int n = n0 + k * 32;
    float acc = 0.f;
    #pragma unroll
    for (int i = 0; i < II; ++i) acc += xs[n][i] * wv[o][i];  // xs column access: padded
    bp[n] += acc;                                             // coalesced in n
  }
}

extern "C" void kernel_launch(void* const* d_in, const int* in_sizes, int n_in,
                              void* d_out, int out_size, void* d_ws, size_t ws_size,
                              hipStream_t stream) {
  const float* x = (const float*)d_in[0];   // [B,N,C,I]
  const float* W = (const float*)d_in[1];   // [C,O,I,J]
  (void)in_sizes; (void)n_in;               // d_in[2] = number_of_nodes (fixed 128)
  float* out = (float*)d_out; (void)out_size;

  float* ws   = (float*)d_ws;
  float* bij  = ws;                                   // 2,097,152 floats (8 MB)
  float* mx   = bij + (size_t)BB * OO * CC * NN;      // 1024
  float* rinv = mx + BB * OO;                         // 1024
  float* cx   = rinv + BB * OO;                       // 524,288
  float* v    = cx + (size_t)BB * CC * OO * II;       // 32,768
  (void)ws_size;  // total ~10.6 MB

  hipMemsetAsync(bij, 0, (size_t)BB * OO * CC * NN * sizeof(float), stream);

  for (int t = 0; t < 3; ++t) {
    k_softmax_stats<<<BB * OO, 256, 0, stream>>>(bij, mx, rinv);
    k_cx<<<BB * CC, 1024, 0, stream>>>(x, bij, mx, rinv, cx);
    k_squash<<<BB, 1024, 0, stream>>>(cx, W, v, out, t == 2 ? 1 : 0);
    if (t < 2)  // reference's final b_ij update is dead code for the outputs
      k_update<<<BB * CC, 1024, 0, stream>>>(x, W, v, bij);
  }
}

// Round 2
// 188.441 us; speedup vs baseline: 2.5889x; 2.5889x over previous
//
#include <hip/hip_runtime.h>
#include <math.h>

// Problem constants (fixed by the reference):
#define BB 32     // batch
#define NN 128    // nodes
#define CC 16     // in_ch
#define OO 32     // out_ch
#define II 32     // in_dim
#define JJ 32     // out_dim
#define MM (NN*CC)  // 2048 input capsules per (b, out_ch)
static constexpr float EPS_SQ = 1e-11f;

// Workspace (floats):
//   bij [BB][OO][CC][NN]  routing logits (m reordered to (c,n); softmax is
//                         permutation-invariant over m so this is safe)
//   mx  [BB][OO]          row max for softmax
//   rinv[BB][OO]          1/rowsum for softmax
//   cx  [BB][CC][OO][II]  softmax-weighted x: sum_n c * x
//   v   [BB][OO][JJ]      squashed output capsules
//
// Iteration 1's softmax of zeros is uniform 1/2048 -> k_cx uniform flag;
// no memset, no stats kernel for iter 1. bij is first WRITTEN (not +=) by
// k_update_stats(accum=0), which also computes softmax stats for the next
// iteration in-register (block owns the whole 2048-long row).

// XCD-affinity decode: same-b blocks land on the same XCD (blockIdx%8
// heuristic) so x[b] (256 KB) stays in that XCD's 4 MB L2.
__device__ inline void decode_bo(int bid, int& b, int& o) {
  int xcd = bid & 7, t = bid >> 3;
  b = xcd * 4 + (t & 3);
  o = t >> 2;
}

// ---- cx[b,c,o,i] = sum_n coef[o,n] * x[b,n,c,i];  block per (b,c) ----
__global__ __launch_bounds__(1024) void k_cx(
    const float* __restrict__ x, const float* __restrict__ bij,
    const float* __restrict__ mx, const float* __restrict__ rinv,
    float* __restrict__ cx, int uniform) {
  int b = blockIdx.x / CC, c = blockIdx.x % CC;
  __shared__ float coef[OO][NN];       // 16 KB
  __shared__ float xs[NN][II + 1];     // ~16.5 KB, +1 pad (conflict-free columns)
  int tid = threadIdx.x;
  #pragma unroll
  for (int k = 0; k < 4; ++k) {
    int idx = tid + k * 1024;          // = o*NN + n, coalesced in n
    int o = idx >> 7, n = idx & 127;
    int row = b * OO + o;
    coef[o][n] = uniform ? (1.0f / (float)MM)
                         : __expf(bij[((size_t)row * CC + c) * NN + n] - mx[row]) * rinv[row];
  }
  #pragma unroll
  for (int k = 0; k < 4; ++k) {
    int idx = tid + k * 1024;          // = n*II + i, coalesced in i
    int n = idx >> 5, i = idx & 31;
    xs[n][i] = x[(((size_t)b * NN + n) * CC + c) * II + i];
  }
  __syncthreads();
  int o = tid >> 5, i = tid & 31;
  float acc = 0.f;
  #pragma unroll 8
  for (int n = 0; n < NN; ++n) acc += coef[o][n] * xs[n][i];  // coef broadcast, xs padded
  cx[(((size_t)b * CC + c) * OO + o) * II + i] = acc;
}

// ---- s[b,o,j] = sum_{c,i} cx*W; squash -> v (+ final out). Block per (b,o). ----
__global__ __launch_bounds__(256) void k_squash(
    const float* __restrict__ cx, const float* __restrict__ W,
    float* __restrict__ v, float* __restrict__ out, int write_out) {
  int b, o; decode_bo(blockIdx.x, b, o);
  int tid = threadIdx.x, j = tid & 31, g = tid >> 5;   // 8 groups over c
  const float* cxb = cx + (size_t)b * CC * OO * II;
  float acc = 0.f;
  #pragma unroll
  for (int cc = 0; cc < 2; ++cc) {
    int c = g + cc * 8;
    #pragma unroll
    for (int i = 0; i < II; ++i) {
      // cx: broadcast across the 32 j-lanes; W: j-coalesced
      acc += cxb[(c * OO + o) * II + i] * W[(((size_t)c * OO + o) * II + i) * JJ + j];
    }
  }
  __shared__ float part[8][32];
  part[g][j] = acc;                    // 2-way-per-bank across wave: free
  __syncthreads();
  if (tid < 32) {
    float s = 0.f;
    #pragma unroll
    for (int gg = 0; gg < 8; ++gg) s += part[gg][j];
    float msq = s * s;
    #pragma unroll
    for (int off = 16; off > 0; off >>= 1) msq += __shfl_xor(msq, off);
    float mag = sqrtf(msq) + EPS_SQ;
    float a   = msq / (1.0f + msq);
    float vv  = a * s / mag;
    int row = b * OO + o;
    v[(size_t)row * JJ + j] = vv;
    if (write_out) {
      out[(size_t)row * JJ + j] = vv;                  // v_j: [B,1,O,J] flat
      if (j == 0) out[BB * OO * JJ + row] = a;         // a_j: [B,1,O,1] flat
    }
  }
}

// ---- fused agreement update + softmax stats. Block per (b,o).
//      wv[c,i] = sum_j W[c,o,i,j]*v[b,o,j]  (LDS)
//      row[c,n] = (accum? bij : 0) + sum_i x[b,n,c,i]*wv[c,i]; write row,
//      then block-reduce max / sum-exp -> mx, rinv for the NEXT softmax. ----
__global__ __launch_bounds__(256) void k_update_stats(
    const float* __restrict__ x, const float* __restrict__ W,
    const float* __restrict__ v, float* __restrict__ bij,
    float* __restrict__ mx, float* __restrict__ rinv, int accum) {
  int b, o; decode_bo(blockIdx.x, b, o);
  int tid = threadIdx.x;
  __shared__ float vs[JJ];             // 128 B
  __shared__ float wv[CC][II];         // 2 KB
  __shared__ float red[4], red2[4];
  if (tid < JJ) vs[tid] = v[((size_t)b * OO + o) * JJ + tid];
  __syncthreads();
  #pragma unroll
  for (int k = 0; k < 2; ++k) {        // 512 wv entries / 256 threads
    int ci = tid + k * 256;
    int c = ci >> 5, i = ci & 31;
    const float4* Wr = (const float4*)(W + (((size_t)c * OO + o) * II + i) * JJ);
    float acc = 0.f;
    #pragma unroll
    for (int q = 0; q < 8; ++q) {
      float4 w4 = Wr[q];
      acc += w4.x * vs[q*4+0] + w4.y * vs[q*4+1] + w4.z * vs[q*4+2] + w4.w * vs[q*4+3];
    }
    wv[c][i] = acc;
  }
  __syncthreads();
  float* bp = bij + (size_t)(b * OO + o) * CC * NN;
  float vals[8];
  float m_ = -INFINITY;
  #pragma unroll
  for (int k = 0; k < 8; ++k) {        // 2048 row entries / 256 threads
    int m = tid + k * 256;
    int c = m >> 7, n = m & 127;
    const float4* xr = (const float4*)(x + (((size_t)b * NN + n) * CC + c) * II);
    float acc = 0.f;
    #pragma unroll
    for (int q = 0; q < 8; ++q) {
      float4 x4 = xr[q];
      acc += x4.x * wv[c][q*4+0] + x4.y * wv[c][q*4+1] + x4.z * wv[c][q*4+2] + x4.w * wv[c][q*4+3];
    }
    if (accum) acc += bp[m];           // coalesced in n
    bp[m] = acc;
    vals[k] = acc;
    m_ = fmaxf(m_, acc);
  }
  #pragma unroll
  for (int off = 32; off > 0; off >>= 1) m_ = fmaxf(m_, __shfl_xor(m_, off));
  int wave = tid >> 6;
  if ((tid & 63) == 0) red[wave] = m_;
  __syncthreads();
  m_ = fmaxf(fmaxf(red[0], red[1]), fmaxf(red[2], red[3]));
  float s = 0.f;
  #pragma unroll
  for (int k = 0; k < 8; ++k) s += __expf(vals[k] - m_);
  #pragma unroll
  for (int off = 32; off > 0; off >>= 1) s += __shfl_xor(s, off);
  if ((tid & 63) == 0) red2[wave] = s;
  __syncthreads();
  if (tid == 0) {
    int row = b * OO + o;
    mx[row]   = m_;
    rinv[row] = 1.0f / (red2[0] + red2[1] + red2[2] + red2[3]);
  }
}

extern "C" void kernel_launch(void* const* d_in, const int* in_sizes, int n_in,
                              void* d_out, int out_size, void* d_ws, size_t ws_size,
                              hipStream_t stream) {
  const float* x = (const float*)d_in[0];   // [B,N,C,I]
  const float* W = (const float*)d_in[1];   // [C,O,I,J]
  (void)in_sizes; (void)n_in;               // d_in[2] = number_of_nodes (fixed 128)
  float* out = (float*)d_out; (void)out_size;

  float* ws   = (float*)d_ws;
  float* bij  = ws;                                   // 2,097,152 floats (8 MB)
  float* mx   = bij + (size_t)BB * OO * CC * NN;      // 1024
  float* rinv = mx + BB * OO;                         // 1024
  float* cx   = rinv + BB * OO;                       // 524,288
  float* v    = cx + (size_t)BB * CC * OO * II;       // 32,768
  (void)ws_size;  // total ~10.6 MB

  // iter 1 (uniform softmax — bij rows are all zero)
  k_cx<<<BB * CC, 1024, 0, stream>>>(x, bij, mx, rinv, cx, 1);
  k_squash<<<BB * OO, 256, 0, stream>>>(cx, W, v, out, 0);
  k_update_stats<<<BB * OO, 256, 0, stream>>>(x, W, v, bij, mx, rinv, 0);
  // iter 2
  k_cx<<<BB * CC, 1024, 0, stream>>>(x, bij, mx, rinv, cx, 0);
  k_squash<<<BB * OO, 256, 0, stream>>>(cx, W, v, out, 0);
  k_update_stats<<<BB * OO, 256, 0, stream>>>(x, W, v, bij, mx, rinv, 1);
  // iter 3 (final; reference discards the last b_ij update)
  k_cx<<<BB * CC, 1024, 0, stream>>>(x, bij, mx, rinv, cx, 0);
  k_squash<<<BB * OO, 256, 0, stream>>>(cx, W, v, out, 1);
}